// Round 1
// baseline (198.543 us; speedup 1.0000x reference)
//
#include <hip/hip_runtime.h>
#include <hip/hip_bf16.h>

#define N_NODES 8192
#define N_IN 512
#define N_OUT 512

typedef __bf16 bf16;
typedef __bf16 bf16x4 __attribute__((ext_vector_type(4)));
typedef __bf16 bf16x8 __attribute__((ext_vector_type(8)));
typedef float f32x4 __attribute__((ext_vector_type(4)));

__device__ __forceinline__ void gload16(const void* g, void* l) {
  __builtin_amdgcn_global_load_lds((const __attribute__((address_space(1))) void*)g,
                                   (__attribute__((address_space(3))) void*)l, 16, 0, 0);
}

#define WAITVM(N) asm volatile("s_waitcnt vmcnt(" #N ")" ::: "memory")

// ---- kernel 1: column partial sums of adj + fp32->bf16 convert (one fused pass) ----
__global__ __launch_bounds__(256) void k_colsum_cvt(const float* __restrict__ adj,
                                                    bf16* __restrict__ adjb,
                                                    float* __restrict__ partial) {
  const int tid  = threadIdx.x;
  const int col0 = blockIdx.x * 1024 + tid * 4;
  const int row0 = blockIdx.y * 64;
  float s0 = 0.f, s1 = 0.f, s2 = 0.f, s3 = 0.f;
#pragma unroll 4
  for (int r = 0; r < 64; ++r) {
    const float4 v = *reinterpret_cast<const float4*>(adj + (size_t)(row0 + r) * N_NODES + col0);
    s0 += v.x; s1 += v.y; s2 += v.z; s3 += v.w;
    bf16x4 o = { (bf16)v.x, (bf16)v.y, (bf16)v.z, (bf16)v.w };
    *reinterpret_cast<bf16x4*>(adjb + (size_t)(row0 + r) * N_NODES + col0) = o;
  }
  float4 ps = { s0, s1, s2, s3 };
  *reinterpret_cast<float4*>(partial + (size_t)blockIdx.y * N_NODES + col0) = ps;
}

// ---- kernel 2: d[j] = rsqrt(1 + colsum)  (deterministic reduce over 128 partials) ----
__global__ __launch_bounds__(256) void k_dvec(const float* __restrict__ partial,
                                              float* __restrict__ dv) {
  const int j = blockIdx.x * 256 + threadIdx.x;
  float s = 1.0f;  // +1 from the identity (self-loop)
#pragma unroll 8
  for (int p = 0; p < 128; ++p) s += partial[(size_t)p * N_NODES + j];
  dv[j] = rsqrtf(s);
}

// ---- kernel 3: Hst[k][j] = d[j]*H[j][k]  (transpose+scale, bf16; B^T layout for GEMM1) ----
__global__ __launch_bounds__(256) void k_hst(const float* __restrict__ H,
                                             const float* __restrict__ dv,
                                             bf16* __restrict__ Hst) {
  __shared__ float t[64][65];
  const int tid = threadIdx.x;
  const int j0 = blockIdx.x * 64;
  const int k0 = blockIdx.y * 64;
  const int rr = tid >> 4;         // 0..15
  const int cc = (tid & 15) * 4;   // 0..60
#pragma unroll
  for (int p = 0; p < 4; ++p) {
    const int r = p * 16 + rr;
    const float d = dv[j0 + r];
    float4 v = *reinterpret_cast<const float4*>(H + (size_t)(j0 + r) * N_IN + k0 + cc);
    t[r][cc + 0] = v.x * d; t[r][cc + 1] = v.y * d;
    t[r][cc + 2] = v.z * d; t[r][cc + 3] = v.w * d;
  }
  __syncthreads();
#pragma unroll
  for (int p = 0; p < 4; ++p) {
    const int kr = p * 16 + rr;
    bf16x4 o = { (bf16)t[cc + 0][kr], (bf16)t[cc + 1][kr],
                 (bf16)t[cc + 2][kr], (bf16)t[cc + 3][kr] };
    *reinterpret_cast<bf16x4*>(Hst + (size_t)(k0 + kr) * N_NODES + j0 + cc) = o;
  }
}

// ---- kernel 4: W fp32 -> bf16 (already B^T layout: [NOUT][NIN]) ----
__global__ __launch_bounds__(256) void k_wcvt(const float* __restrict__ W, bf16* __restrict__ Wb) {
  const int i = (blockIdx.x * 256 + threadIdx.x) * 4;
  float4 v = *reinterpret_cast<const float4*>(W + i);
  bf16x4 o = { (bf16)v.x, (bf16)v.y, (bf16)v.z, (bf16)v.w };
  *reinterpret_cast<bf16x4*>(Wb + i) = o;
}

// ---- GEMM: C = A[M x KDIM] @ Bt[128-col-tile x KDIM]^T, 128x128 tile, BK=64, 4 waves ----
// depth-3 prefetch (4 LDS buffers), counted vmcnt, raw barriers, XOR-swizzled LDS.
// EPI=0: Hm[i][c] = d_i*acc + d_i^2*H[i][c]   (bf16 out)
// EPI=1: out[i][c] = tanh(acc + bias[c])      (f32 out)
template<int KDIM, int EPI>
__global__ __launch_bounds__(256, 1) void k_gemm(
    const bf16* __restrict__ A, const bf16* __restrict__ B,
    const float* __restrict__ dvec, const float* __restrict__ Hf,
    const float* __restrict__ bias, bf16* __restrict__ outb, float* __restrict__ outf) {
  constexpr int NT = KDIM / 64;
  __shared__ __attribute__((aligned(128))) char lds[4 * 32768];

  // XCD swizzle: 8 XCDs get 32 contiguous logical blocks; the 4 N-blocks of each
  // M-group are adjacent -> A-tile re-reads are L2-local.
  const int bid = blockIdx.x;
  const int logical = (bid & 7) * 32 + (bid >> 3);
  const int bm0 = (logical >> 2) * 128;
  const int bn0 = (logical & 3) * 128;

  const int tid = threadIdx.x;
  const int wid = tid >> 6;
  const int lane = tid & 63;
  const int wr = wid & 1, wc = wid >> 1;   // 2x2 waves, each 64x64 output

  // staging: linear LDS dest (global_load_lds), INVERSE-swizzled global source (rule #21)
  const int srow = tid >> 3;                           // 0..31 within a 32-row chunk
  const int scol = ((tid & 7) ^ (srow & 7)) << 3;      // swizzled source col (elements)
  const size_t a_src = (size_t)(bm0 + srow) * KDIM + scol;
  const size_t b_src = (size_t)(bn0 + srow) * KDIM + scol;

  // fragment read addressing (swizzled): byte = row*128 + ((kk*64 + fk*16) ^ ((row&7)<<4))
  const int frow = lane & 15;
  const int fk = lane >> 4;                 // 0..3
  const int swz = (lane & 7) << 4;          // row&7 == lane&7 for all fragment rows
  const int a_row_byte = (wr * 64 + frow) * 128;
  const int b_row_byte = 16384 + (wc * 64 + frow) * 128;

  f32x4 acc[4][4] = {};

  auto stage = [&](int t) {
    const int buf = t & 3;
    char* lbase = lds + buf * 32768;
    const bf16* ag = A + a_src + (size_t)t * 64;
    const bf16* bg = B + b_src + (size_t)t * 64;
#pragma unroll
    for (int ch = 0; ch < 4; ++ch) {
      gload16(ag + (size_t)(ch * 32) * KDIM, lbase + ch * 4096 + wid * 1024);
      gload16(bg + (size_t)(ch * 32) * KDIM, lbase + 16384 + ch * 4096 + wid * 1024);
    }
  };

  auto compute = [&](int t) {
    const char* lbase = lds + (t & 3) * 32768;
#pragma unroll
    for (int kk = 0; kk < 2; ++kk) {
      const int colb = (kk * 64 + fk * 16) ^ swz;
      bf16x8 av[4], bv[4];
#pragma unroll
      for (int m = 0; m < 4; ++m)
        av[m] = *reinterpret_cast<const bf16x8*>(lbase + a_row_byte + m * 2048 + colb);
#pragma unroll
      for (int n = 0; n < 4; ++n)
        bv[n] = *reinterpret_cast<const bf16x8*>(lbase + b_row_byte + n * 2048 + colb);
#pragma unroll
      for (int m = 0; m < 4; ++m)
#pragma unroll
        for (int n = 0; n < 4; ++n)
          acc[m][n] = __builtin_amdgcn_mfma_f32_16x16x32_bf16(av[m], bv[n], acc[m][n], 0, 0, 0);
    }
  };

  stage(0); stage(1); stage(2);
  for (int t = 0; t < NT; ++t) {
    if (t + 3 < NT) stage(t + 3);
    const int ahead = NT - 1 - t;
    if (ahead >= 3)      WAITVM(24);   // 3 tiles x 8 loads in flight, tile t drained
    else if (ahead == 2) WAITVM(16);
    else if (ahead == 1) WAITVM(8);
    else                 WAITVM(0);
    __builtin_amdgcn_s_barrier();
    asm volatile("" ::: "memory");     // no LDS reads hoist above the barrier
    compute(t);
    asm volatile("" ::: "memory");     // no LDS reads sink below the barrier
    __builtin_amdgcn_s_barrier();      // buffer t&3 is rewritten at iter t+1 (stage t+4)
  }

  // epilogue: C/D layout col = lane&15, row = (lane>>4)*4 + j
#pragma unroll
  for (int m = 0; m < 4; ++m) {
#pragma unroll
    for (int j = 0; j < 4; ++j) {
      const int grow = bm0 + wr * 64 + m * 16 + (lane >> 4) * 4 + j;
      if constexpr (EPI == 0) {
        const float d = dvec[grow];
        const float d2 = d * d;
        const float* hrow = Hf + (size_t)grow * N_IN;
        bf16* orow = outb + (size_t)grow * N_IN;
#pragma unroll
        for (int n = 0; n < 4; ++n) {
          const int gcol = bn0 + wc * 64 + n * 16 + (lane & 15);
          orow[gcol] = (bf16)(d * acc[m][n][j] + d2 * hrow[gcol]);
        }
      } else {
        float* orow = outf + (size_t)grow * N_OUT;
#pragma unroll
        for (int n = 0; n < 4; ++n) {
          const int gcol = bn0 + wc * 64 + n * 16 + (lane & 15);
          float v = acc[m][n][j] + bias[gcol];
          v = fminf(fmaxf(v, -15.f), 15.f);
          const float e = __expf(2.f * v);
          orow[gcol] = (e - 1.f) / (e + 1.f);
        }
      }
    }
  }
}

extern "C" void kernel_launch(void* const* d_in, const int* in_sizes, int n_in,
                              void* d_out, int out_size, void* d_ws, size_t ws_size,
                              hipStream_t stream) {
  const float* H   = (const float*)d_in[0];
  const float* adj = (const float*)d_in[1];
  const float* W   = (const float*)d_in[2];
  const float* b   = (const float*)d_in[3];
  float* out = (float*)d_out;
  char* ws = (char*)d_ws;

  bf16*  adjb = (bf16*)(ws);                    // 8192*8192*2 = 134217728
  bf16*  Hst  = (bf16*)(ws + 134217728);        // 512*8192*2  = 8388608
  bf16*  Hm   = (bf16*)(ws + 142606336);        // 8192*512*2  = 8388608
  bf16*  Wb   = (bf16*)(ws + 150994944);        // 512*512*2   = 524288
  float* part = (float*)(ws + 151519232);       // 128*8192*4  = 4194304
  float* dv   = (float*)(ws + 155713536);       // 8192*4      = 32768

  k_colsum_cvt<<<dim3(8, 128), 256, 0, stream>>>(adj, adjb, part);
  k_dvec<<<32, 256, 0, stream>>>(part, dv);
  k_hst<<<dim3(128, 8), 256, 0, stream>>>(H, dv, Hst);
  k_wcvt<<<256, 256, 0, stream>>>(W, Wb);
  // Hm = d_i*(adj @ (d.*H)) + d_i^2*H   (bf16)
  k_gemm<8192, 0><<<256, 256, 0, stream>>>(adjb, Hst, dv, H, nullptr, Hm, nullptr);
  // out = tanh(Hm @ W^T + b)            (f32)
  k_gemm<512, 1><<<256, 256, 0, stream>>>(Hm, Wb, nullptr, nullptr, b, nullptr, out);
}